// Round 2
// baseline (334.095 us; speedup 1.0000x reference)
//
#include <hip/hip_runtime.h>
#include <hip/hip_fp16.h>
#include <cstdint>

#define D 128
#define NLEV 16
#define TPB 512
#define WPB (TPB / 64)
#define RPW 8
#define NBATCH 4
#define ROWS_PER_BLOCK (WPB * RPW * NBATCH)  // 256

__device__ __forceinline__ float rlane_f(float v, int l) {
    return __int_as_float(__builtin_amdgcn_readlane(__float_as_int(v), l));
}
__device__ __forceinline__ float sload_f(float v) {
    return __int_as_float(__builtin_amdgcn_readfirstlane(__float_as_int(v)));
}

__global__ __launch_bounds__(TPB, 4)
void tq_main(const float* __restrict__ x, const float* __restrict__ Pi,
             const float* __restrict__ cbk, float* __restrict__ out, int nrows) {
    __shared__ float lds[D * D];  // 64 KiB: Pi^T for phase 1, then Pi for phase 2

    const int tid  = threadIdx.x;
    const int lane = tid & 63;
    const int wave = tid >> 6;

    // ---- stage LA[j][i] = Pi[i][j] (transposed) for matvec1 ----
    for (int k = tid; k < D * D; k += TPB) {
        lds[(k & (D - 1)) * D + (k >> 7)] = Pi[k];
    }

    // codebook + decision boundaries, forced wave-uniform (SGPR)
    float code[NLEV], mid[NLEV - 1];
#pragma unroll
    for (int k = 0; k < NLEV; ++k) code[k] = sload_f(cbk[k]);
#pragma unroll
    for (int k = 0; k < NLEV - 1; ++k) mid[k] = 0.5f * (code[k] + code[k + 1]);

    const float sqrt_d = 11.313708498984761f;  // sqrt(128)

    __syncthreads();

    const int gw = blockIdx.x * WPB + wave;

    uint32_t cpk[NBATCH][RPW];  // packed fp16 pair (c[2l], c[2l+1]) * h/sqrt_d per row

    // ---------------- phase 1: compress (rotate + quantize) ----------------
#pragma unroll
    for (int b = 0; b < NBATCH; ++b) {
        const int row0 = (gw * NBATCH + b) * RPW;
        float2 xv[RPW];
#pragma unroll
        for (int r = 0; r < RPW; ++r) {
            int row = row0 + r;
            if (row >= nrows) row = nrows - 1;  // clamp (safe dup work), store is guarded
            xv[r] = *reinterpret_cast<const float2*>(x + (size_t)row * D + 2 * lane);
        }
        float s1[RPW], s2l[RPW];
#pragma unroll
        for (int r = 0; r < RPW; ++r) {
            float ns = fmaf(xv[r].x, xv[r].x, xv[r].y * xv[r].y);
#pragma unroll
            for (int off = 32; off; off >>= 1) ns += __shfl_xor(ns, off, 64);
            const float nrm = sqrtf(ns);
            s1[r] = sqrt_d / fmaxf(nrm, 1e-8f);                 // fold unit-norm + sqrt_d
            const float h = __half2float(__float2half(nrm));    // fp16 round-trip of norm
            s2l[r] = h / sqrt_d;                                // fold h and 1/sqrt_d
        }
        float y0[RPW], y1[RPW];
#pragma unroll
        for (int r = 0; r < RPW; ++r) { y0[r] = 0.f; y1[r] = 0.f; }
        // y_i = sum_j Pi[i][j] * x[j];  lane owns i = 2*lane, 2*lane+1
        for (int j = 0; j < D; j += 2) {
            const float2 p0 = *reinterpret_cast<const float2*>(lds + j * D + 2 * lane);
            const float2 p1 = *reinterpret_cast<const float2*>(lds + (j + 1) * D + 2 * lane);
            const int sl = j >> 1;
#pragma unroll
            for (int r = 0; r < RPW; ++r) {
                const float xa = rlane_f(xv[r].x, sl);  // x[j]   (j even)
                const float xb = rlane_f(xv[r].y, sl);  // x[j+1] (odd)
                y0[r] = fmaf(p0.x, xa, y0[r]);
                y1[r] = fmaf(p0.y, xa, y1[r]);
                y0[r] = fmaf(p1.x, xb, y0[r]);
                y1[r] = fmaf(p1.y, xb, y1[r]);
            }
        }
        // branchless nearest-level quantize (ties -> lower index, matches argmin)
#pragma unroll
        for (int r = 0; r < RPW; ++r) {
            const float ya = y0[r] * s1[r];
            const float yb = y1[r] * s1[r];
            float ca = code[0], cb2 = code[0];
#pragma unroll
            for (int k = 0; k < NLEV - 1; ++k) {
                ca  = (ya > mid[k]) ? code[k + 1] : ca;
                cb2 = (yb > mid[k]) ? code[k + 1] : cb2;
            }
            const float sc = s2l[r];
            const unsigned short ha = __half_as_ushort(__float2half(ca * sc));
            const unsigned short hb = __half_as_ushort(__float2half(cb2 * sc));
            cpk[b][r] = (uint32_t)ha | ((uint32_t)hb << 16);
        }
    }

    __syncthreads();
    // ---- restage: LB = Pi row-major for matvec2 ----
    for (int k = tid; k < D * D; k += TPB) lds[k] = Pi[k];
    __syncthreads();

    // ---------------- phase 2: decompress (inverse rotate) ----------------
#pragma unroll
    for (int b = 0; b < NBATCH; ++b) {
        const int row0 = (gw * NBATCH + b) * RPW;
        float o0[RPW], o1[RPW];
#pragma unroll
        for (int r = 0; r < RPW; ++r) { o0[r] = 0.f; o1[r] = 0.f; }
        // out_i = sum_j Pi[j][i] * c[j]
        for (int j = 0; j < D; j += 2) {
            const float2 p0 = *reinterpret_cast<const float2*>(lds + j * D + 2 * lane);
            const float2 p1 = *reinterpret_cast<const float2*>(lds + (j + 1) * D + 2 * lane);
            const int sl = j >> 1;
#pragma unroll
            for (int r = 0; r < RPW; ++r) {
                const uint32_t u = (uint32_t)__builtin_amdgcn_readlane((int)cpk[b][r], sl);
                const float ca  = __half2float(__ushort_as_half((unsigned short)(u & 0xffffu)));
                const float cb2 = __half2float(__ushort_as_half((unsigned short)(u >> 16)));
                o0[r] = fmaf(p0.x, ca, o0[r]);
                o1[r] = fmaf(p0.y, ca, o1[r]);
                o0[r] = fmaf(p1.x, cb2, o0[r]);
                o1[r] = fmaf(p1.y, cb2, o1[r]);
            }
        }
#pragma unroll
        for (int r = 0; r < RPW; ++r) {
            const int row = row0 + r;
            if (row < nrows) {
                *reinterpret_cast<float2*>(out + (size_t)row * D + 2 * lane) =
                    make_float2(o0[r], o1[r]);
            }
        }
    }
}

extern "C" void kernel_launch(void* const* d_in, const int* in_sizes, int n_in,
                              void* d_out, int out_size, void* d_ws, size_t ws_size,
                              hipStream_t stream) {
    const float* x   = (const float*)d_in[0];
    const float* Pi  = (const float*)d_in[1];
    const float* cbk = (const float*)d_in[2];
    float* out = (float*)d_out;

    const int nrows = in_sizes[0] / D;
    const int grid  = (nrows + ROWS_PER_BLOCK - 1) / ROWS_PER_BLOCK;

    tq_main<<<dim3(grid), dim3(TPB), 0, stream>>>(x, Pi, cbk, out, nrows);
}

// Round 3
// 333.450 us; speedup vs baseline: 1.0019x; 1.0019x over previous
//
#include <hip/hip_runtime.h>
#include <hip/hip_fp16.h>
#include <cstdint>

#define D 128
#define NLEV 16
#define TPB 512
#define WPB (TPB / 64)   // 8 waves per block
#define RPW 8            // rows per wave per batch
#define NBATCH 2
#define ROWS_PER_BLOCK (WPB * RPW * NBATCH)  // 128

__device__ __forceinline__ float rlane_f(float v, int l) {
    return __int_as_float(__builtin_amdgcn_readlane(__float_as_int(v), l));
}
__device__ __forceinline__ float sload_f(float v) {
    return __int_as_float(__builtin_amdgcn_readfirstlane(__float_as_int(v)));
}

__global__ __launch_bounds__(TPB, 2)
void tq_main(const float* __restrict__ x, const float* __restrict__ Pi,
             const float* __restrict__ cbk, float* __restrict__ out, int nrows) {
    __shared__ float lds[D * D];  // 64 KiB: Pi^T for phase 1, then Pi for phase 2

    const int tid  = threadIdx.x;
    const int lane = tid & 63;
    const int wave = tid >> 6;

    // ---- stage LA[j][i] = Pi[i][j] (transposed) for phase 1 ----
    // Linear (conflict-free) LDS writes; the transpose gather happens on the
    // global side (Pi is 64 KB -> L2/L3-resident, latency hidden by waves).
    for (int k = tid; k < D * D; k += TPB) {
        lds[k] = Pi[(k & (D - 1)) * D + (k >> 7)];
    }

    // codebook + decision boundaries, forced wave-uniform (SGPR)
    float code[NLEV], mid[NLEV - 1];
#pragma unroll
    for (int k = 0; k < NLEV; ++k) code[k] = sload_f(cbk[k]);
#pragma unroll
    for (int k = 0; k < NLEV - 1; ++k) mid[k] = 0.5f * (code[k] + code[k + 1]);

    const float sqrt_d = 11.313708498984761f;  // sqrt(128)

    __syncthreads();

    const int gw = blockIdx.x * WPB + wave;

    uint32_t cpk[NBATCH][RPW];  // packed fp16 pair (c[2l], c[2l+1]) * h/sqrt_d per row

    // ---------------- phase 1: compress (rotate + quantize) ----------------
#pragma unroll
    for (int b = 0; b < NBATCH; ++b) {
        const int row0 = (gw * NBATCH + b) * RPW;
        float2 xv[RPW];
#pragma unroll
        for (int r = 0; r < RPW; ++r) {
            int row = row0 + r;
            if (row >= nrows) row = nrows - 1;  // clamp (safe dup work), store is guarded
            xv[r] = *reinterpret_cast<const float2*>(x + (size_t)row * D + 2 * lane);
        }
        float ns[RPW];  // keep only the reduced sum-of-squares live (8 regs)
#pragma unroll
        for (int r = 0; r < RPW; ++r) {
            float s = fmaf(xv[r].x, xv[r].x, xv[r].y * xv[r].y);
#pragma unroll
            for (int off = 32; off; off >>= 1) s += __shfl_xor(s, off, 64);
            ns[r] = s;
        }
        float y0[RPW], y1[RPW];
#pragma unroll
        for (int r = 0; r < RPW; ++r) { y0[r] = 0.f; y1[r] = 0.f; }
        // y_i = sum_j Pi[i][j] * x[j];  lane owns i = 2*lane, 2*lane+1
#pragma unroll 4
        for (int j = 0; j < D; j += 2) {
            const float2 p0 = *reinterpret_cast<const float2*>(lds + j * D + 2 * lane);
            const float2 p1 = *reinterpret_cast<const float2*>(lds + (j + 1) * D + 2 * lane);
            const int sl = j >> 1;
#pragma unroll
            for (int r = 0; r < RPW; ++r) {
                const float xa = rlane_f(xv[r].x, sl);  // x[j]   (j even)
                const float xb = rlane_f(xv[r].y, sl);  // x[j+1] (odd)
                y0[r] = fmaf(p0.x, xa, y0[r]);
                y1[r] = fmaf(p0.y, xa, y1[r]);
                y0[r] = fmaf(p1.x, xb, y0[r]);
                y1[r] = fmaf(p1.y, xb, y1[r]);
            }
        }
        // branchless nearest-level quantize (ties -> lower index, matches argmin)
#pragma unroll
        for (int r = 0; r < RPW; ++r) {
            const float nrm = sqrtf(ns[r]);
            const float s1  = sqrt_d / fmaxf(nrm, 1e-8f);       // fold unit-norm + sqrt_d
            const float h   = __half2float(__float2half(nrm));  // fp16 round-trip of norm
            const float sc  = h / sqrt_d;                       // fold h and 1/sqrt_d
            const float ya = y0[r] * s1;
            const float yb = y1[r] * s1;
            float ca = code[0], cb2 = code[0];
#pragma unroll
            for (int k = 0; k < NLEV - 1; ++k) {
                ca  = (ya > mid[k]) ? code[k + 1] : ca;
                cb2 = (yb > mid[k]) ? code[k + 1] : cb2;
            }
            const unsigned short ha = __half_as_ushort(__float2half(ca * sc));
            const unsigned short hb = __half_as_ushort(__float2half(cb2 * sc));
            cpk[b][r] = (uint32_t)ha | ((uint32_t)hb << 16);
        }
    }

    __syncthreads();
    // ---- restage: LB = Pi row-major for phase 2 (linear both sides) ----
    for (int k = tid; k < D * D; k += TPB) lds[k] = Pi[k];
    __syncthreads();

    // ---------------- phase 2: decompress (inverse rotate) ----------------
#pragma unroll
    for (int b = 0; b < NBATCH; ++b) {
        const int row0 = (gw * NBATCH + b) * RPW;
        float o0[RPW], o1[RPW];
#pragma unroll
        for (int r = 0; r < RPW; ++r) { o0[r] = 0.f; o1[r] = 0.f; }
        // out_i = sum_j Pi[j][i] * c[j]
#pragma unroll 4
        for (int j = 0; j < D; j += 2) {
            const float2 p0 = *reinterpret_cast<const float2*>(lds + j * D + 2 * lane);
            const float2 p1 = *reinterpret_cast<const float2*>(lds + (j + 1) * D + 2 * lane);
            const int sl = j >> 1;
#pragma unroll
            for (int r = 0; r < RPW; ++r) {
                const uint32_t u = (uint32_t)__builtin_amdgcn_readlane((int)cpk[b][r], sl);
                __half2 h2 = *reinterpret_cast<const __half2*>(&u);
                const float2 cf = __half22float2(h2);
                o0[r] = fmaf(p0.x, cf.x, o0[r]);
                o1[r] = fmaf(p0.y, cf.x, o1[r]);
                o0[r] = fmaf(p1.x, cf.y, o0[r]);
                o1[r] = fmaf(p1.y, cf.y, o1[r]);
            }
        }
#pragma unroll
        for (int r = 0; r < RPW; ++r) {
            const int row = row0 + r;
            if (row < nrows) {
                *reinterpret_cast<float2*>(out + (size_t)row * D + 2 * lane) =
                    make_float2(o0[r], o1[r]);
            }
        }
    }
}

extern "C" void kernel_launch(void* const* d_in, const int* in_sizes, int n_in,
                              void* d_out, int out_size, void* d_ws, size_t ws_size,
                              hipStream_t stream) {
    const float* x   = (const float*)d_in[0];
    const float* Pi  = (const float*)d_in[1];
    const float* cbk = (const float*)d_in[2];
    float* out = (float*)d_out;

    const int nrows = in_sizes[0] / D;
    const int grid  = (nrows + ROWS_PER_BLOCK - 1) / ROWS_PER_BLOCK;

    tq_main<<<dim3(grid), dim3(TPB), 0, stream>>>(x, Pi, cbk, out, nrows);
}

// Round 4
// 234.746 us; speedup vs baseline: 1.4232x; 1.4205x over previous
//
#include <hip/hip_runtime.h>
#include <hip/hip_fp16.h>
#include <cstdint>

#define D 128
#define NLEV 16
#define TPB 512
#define WPB 8            // waves per block
#define RPW 8            // rows per wave per batch
#define NBATCH 2
#define ROWS_PER_WAVE 16
#define ROWS_PER_BLOCK (WPB * ROWS_PER_WAVE)  // 128

typedef __attribute__((ext_vector_type(8))) short bf16x8;  // MFMA A/B frag (4 VGPR)
typedef __attribute__((ext_vector_type(4))) float f32x4;   // MFMA C/D frag

__device__ __forceinline__ float rlane_f(float v, int l) {
    return __int_as_float(__builtin_amdgcn_readlane(__float_as_int(v), l));
}
__device__ __forceinline__ float sload_f(float v) {
    return __int_as_float(__builtin_amdgcn_readfirstlane(__float_as_int(v)));
}
__device__ __forceinline__ unsigned short f32_bf16(float f) {  // RNE
    uint32_t u = __float_as_uint(f);
    return (unsigned short)((u + 0x7fffu + ((u >> 16) & 1u)) >> 16);
}
__device__ __forceinline__ float bf16_f32(unsigned short h) {
    return __uint_as_float(((uint32_t)h) << 16);
}

// ---- K0: prepack PiT (fp32) and Pi as hi/lo bf16 MFMA-B fragments ----
// B-frag layout (16x16x32, D[m][n] = sum_k A[m][k]B[k][n]):
//   lane l supplies B[(l>>4)*8 + e][l&15]; frag (it,kf) covers n=it*16..+15, k=kf*32..+31.
// Stored fragment-major: Bhi[((it*4+kf)*64 + l)*8 + e]  -> lane reads one b128.
__global__ void tq_prepack(const float* __restrict__ Pi, float* __restrict__ PiT,
                           unsigned short* __restrict__ Bhi, unsigned short* __restrict__ Blo) {
    const int t = blockIdx.x * blockDim.x + threadIdx.x;  // 0..16383
    // PiT[j][i] = Pi[i][j]
    PiT[t] = Pi[(t & (D - 1)) * D + (t >> 7)];
    // fragment element
    const int e = t & 7, l = (t >> 3) & 63, f = t >> 9;   // f = it*4+kf (0..31)
    const int kf = f & 3, it = f >> 2;
    const int k = kf * 32 + (l >> 4) * 8 + e;
    const int i = it * 16 + (l & 15);
    const float v = Pi[k * D + i];
    const unsigned short hi = f32_bf16(v);
    Bhi[t] = hi;
    Blo[t] = f32_bf16(v - bf16_f32(hi));
}

// ---- K1: compress (fp32 VALU, bit-identical to R3) + decompress (bf16 MFMA) ----
__global__ __launch_bounds__(TPB, 3)
void tq_main(const float* __restrict__ x, const float* __restrict__ PiT,
             const unsigned short* __restrict__ Bhi, const unsigned short* __restrict__ Blo,
             const float* __restrict__ cbk, float* __restrict__ out, int nrows) {
    __shared__ uint32_t lds_u[8192];        // 32 KiB: PiT half-tiles, then packed codes
    float* ldsP = (float*)lds_u;

    const int tid  = threadIdx.x;
    const int lane = tid & 63;
    const int wave = tid >> 6;

    // codebook + decision boundaries, wave-uniform (SGPR)
    float code[NLEV], mid[NLEV - 1];
#pragma unroll
    for (int k = 0; k < NLEV; ++k) code[k] = sload_f(cbk[k]);
#pragma unroll
    for (int k = 0; k < NLEV - 1; ++k) mid[k] = 0.5f * (code[k] + code[k + 1]);

    const float sqrt_d = 11.313708498984761f;  // sqrt(128)

    const int row0 = (blockIdx.x * WPB + wave) * ROWS_PER_WAVE;

    // ---- load x for all 16 rows of this wave ----
    float2 xv[NBATCH][RPW];
#pragma unroll
    for (int b = 0; b < NBATCH; ++b)
#pragma unroll
        for (int r = 0; r < RPW; ++r) {
            int row = row0 + b * RPW + r;
            if (row >= nrows) row = nrows - 1;          // clamp; stores are guarded
            xv[b][r] = *reinterpret_cast<const float2*>(x + (size_t)row * D + 2 * lane);
        }

    // ---- norms (same op order as R3) ----
    float ns[NBATCH][RPW];
#pragma unroll
    for (int b = 0; b < NBATCH; ++b)
#pragma unroll
        for (int r = 0; r < RPW; ++r) {
            float s = fmaf(xv[b][r].x, xv[b][r].x, xv[b][r].y * xv[b][r].y);
#pragma unroll
            for (int off = 32; off; off >>= 1) s += __shfl_xor(s, off, 64);
            ns[b][r] = s;
        }

    float y0[NBATCH][RPW], y1[NBATCH][RPW];
#pragma unroll
    for (int b = 0; b < NBATCH; ++b)
#pragma unroll
        for (int r = 0; r < RPW; ++r) { y0[b][r] = 0.f; y1[b][r] = 0.f; }

    // ---- matvec1 in two 32 KiB PiT halves; per-row j order identical to R3 ----
    for (int h = 0; h < 2; ++h) {
        __syncthreads();  // previous LDS contents no longer needed
        for (int kk = tid; kk < 64 * D; kk += TPB) ldsP[kk] = PiT[h * 64 * D + kk];
        __syncthreads();
#pragma unroll 4
        for (int jj = 0; jj < 64; jj += 2) {
            const float2 p0 = *reinterpret_cast<const float2*>(ldsP + jj * D + 2 * lane);
            const float2 p1 = *reinterpret_cast<const float2*>(ldsP + (jj + 1) * D + 2 * lane);
            const int sl = (h * 64 + jj) >> 1;
#pragma unroll
            for (int b = 0; b < NBATCH; ++b)
#pragma unroll
                for (int r = 0; r < RPW; ++r) {
                    const float xa = rlane_f(xv[b][r].x, sl);
                    const float xb = rlane_f(xv[b][r].y, sl);
                    y0[b][r] = fmaf(p0.x, xa, y0[b][r]);
                    y1[b][r] = fmaf(p0.y, xa, y1[b][r]);
                    y0[b][r] = fmaf(p1.x, xb, y0[b][r]);
                    y1[b][r] = fmaf(p1.y, xb, y1[b][r]);
                }
        }
    }

    // ---- quantize (identical to R3) ----
    uint32_t cpk[NBATCH][RPW];
#pragma unroll
    for (int b = 0; b < NBATCH; ++b)
#pragma unroll
        for (int r = 0; r < RPW; ++r) {
            const float nrm = sqrtf(ns[b][r]);
            const float s1  = sqrt_d / fmaxf(nrm, 1e-8f);
            const float hh  = __half2float(__float2half(nrm));
            const float sc  = hh / sqrt_d;
            const float ya = y0[b][r] * s1;
            const float yb = y1[b][r] * s1;
            float ca = code[0], cb2 = code[0];
#pragma unroll
            for (int k = 0; k < NLEV - 1; ++k) {
                ca  = (ya > mid[k]) ? code[k + 1] : ca;
                cb2 = (yb > mid[k]) ? code[k + 1] : cb2;
            }
            const unsigned short ha = __half_as_ushort(__float2half(ca * sc));
            const unsigned short hb = __half_as_ushort(__float2half(cb2 * sc));
            cpk[b][r] = (uint32_t)ha | ((uint32_t)hb << 16);
        }

    __syncthreads();  // all PiT reads done before overwriting LDS with codes

    // ---- codes -> LDS (XOR-swizzled rows; read back as MFMA A-frags) ----
#pragma unroll
    for (int b = 0; b < NBATCH; ++b)
#pragma unroll
        for (int r = 0; r < RPW; ++r) {
            const int r16 = b * RPW + r;
            lds_u[(wave * 16 + r16) * 64 + (lane ^ ((r16 & 7) << 2))] = cpk[b][r];
        }
    __syncthreads();

    // ---- phase 2: out[16 x 128] = codes @ Pi via split-bf16 MFMA ----
    const int m  = lane & 15;   // A row / D col
    const int kb = lane >> 4;   // k-subblock / D row-block
    bf16x8 ahi[4], alo[4];
#pragma unroll
    for (int kf = 0; kf < 4; ++kf) {
        const int idx = (wave * 16 + m) * 64 + ((kf * 16 + kb * 4) ^ ((m & 7) << 2));
        const uint4 u = *reinterpret_cast<const uint4*>(lds_u + idx);
#pragma unroll
        for (int q = 0; q < 4; ++q) {
            const uint32_t w = ((const uint32_t*)&u)[q];
            const float f0 = __half2float(__ushort_as_half((unsigned short)(w & 0xffffu)));
            const float f1 = __half2float(__ushort_as_half((unsigned short)(w >> 16)));
            const unsigned short h0 = f32_bf16(f0);
            const unsigned short h1 = f32_bf16(f1);
            ahi[kf][2 * q]     = (short)h0;
            ahi[kf][2 * q + 1] = (short)h1;
            alo[kf][2 * q]     = (short)f32_bf16(f0 - bf16_f32(h0));  // exact residual of fp16 value
            alo[kf][2 * q + 1] = (short)f32_bf16(f1 - bf16_f32(h1));
        }
    }
#pragma unroll
    for (int it = 0; it < 8; ++it) {
        f32x4 a = {0.f, 0.f, 0.f, 0.f};
#pragma unroll
        for (int kf = 0; kf < 4; ++kf) {
            const size_t fi = (size_t)((it * 4 + kf) * 64 + lane) * 8;
            const bf16x8 bh = *reinterpret_cast<const bf16x8*>(Bhi + fi);
            const bf16x8 bl = *reinterpret_cast<const bf16x8*>(Blo + fi);
            a = __builtin_amdgcn_mfma_f32_16x16x32_bf16(ahi[kf], bh, a, 0, 0, 0);
            a = __builtin_amdgcn_mfma_f32_16x16x32_bf16(alo[kf], bh, a, 0, 0, 0);
            a = __builtin_amdgcn_mfma_f32_16x16x32_bf16(ahi[kf], bl, a, 0, 0, 0);
        }
#pragma unroll
        for (int reg = 0; reg < 4; ++reg) {
            const int row = row0 + kb * 4 + reg;       // C/D: row=(lane>>4)*4+reg  [m89]
            if (row < nrows) out[(size_t)row * D + it * 16 + m] = a[reg];
        }
    }
}

extern "C" void kernel_launch(void* const* d_in, const int* in_sizes, int n_in,
                              void* d_out, int out_size, void* d_ws, size_t ws_size,
                              hipStream_t stream) {
    const float* x   = (const float*)d_in[0];
    const float* Pi  = (const float*)d_in[1];
    const float* cbk = (const float*)d_in[2];
    float* out = (float*)d_out;

    float*          PiT = (float*)d_ws;                              // 64 KiB
    unsigned short* Bhi = (unsigned short*)((char*)d_ws + 65536);    // 32 KiB
    unsigned short* Blo = (unsigned short*)((char*)d_ws + 98304);    // 32 KiB

    const int nrows = in_sizes[0] / D;
    const int grid  = (nrows + ROWS_PER_BLOCK - 1) / ROWS_PER_BLOCK;

    tq_prepack<<<dim3(64), dim3(256), 0, stream>>>(Pi, PiT, Bhi, Blo);
    tq_main<<<dim3(grid), dim3(TPB), 0, stream>>>(x, PiT, Bhi, Blo, cbk, out, nrows);
}